// Round 1
// baseline (6630.531 us; speedup 1.0000x reference)
//
#include <hip/hip_runtime.h>
#include <cstdint>
#include <cstddef>

#define B_    8
#define N_    2048
#define D_    1024
#define EO_   4
#define EI_   4
#define H_    4096
#define CO_   640
#define CI_   200
#define NTOK  (B_*N_)         // 16384
#define NSLOT (EO_*B_*CO_)    // 20480 outer slots
#define NISL  (EO_*EI_*B_*CI_) // 25600 inner slots
#define EPS_  1e-9f

// ---------------- K1: outer gate logits [B,N,EO] ----------------
__global__ void k_outer_logits(const float* __restrict__ x, const float* __restrict__ wgo,
                               float* __restrict__ logits) {
  int wave = (blockIdx.x * blockDim.x + threadIdx.x) >> 6;  // token id
  int lane = threadIdx.x & 63;
  const float*  xr = x + (size_t)wave * D_;
  const float4* w4 = (const float4*)wgo;   // [d] -> 4 experts
  float a0 = 0.f, a1 = 0.f, a2 = 0.f, a3 = 0.f;
#pragma unroll
  for (int i = 0; i < 16; ++i) {
    int d = i * 64 + lane;
    float xv = xr[d];
    float4 wv = w4[d];
    a0 += xv * wv.x; a1 += xv * wv.y; a2 += xv * wv.z; a3 += xv * wv.w;
  }
#pragma unroll
  for (int o = 32; o > 0; o >>= 1) {
    a0 += __shfl_xor(a0, o, 64); a1 += __shfl_xor(a1, o, 64);
    a2 += __shfl_xor(a2, o, 64); a3 += __shfl_xor(a3, o, 64);
  }
  if (lane == 0) ((float4*)logits)[wave] = make_float4(a0, a1, a2, a3);
}

// ---------------- K2: outer top-2 gating (one wave per batch) ----------------
__global__ void k_outer_gate(const float* __restrict__ logits,
                             int* __restrict__ t_idx1, int* __restrict__ t_idx2,
                             int* __restrict__ t_pos1, int* __restrict__ t_pos2,
                             float* __restrict__ t_g1, float* __restrict__ t_g2,
                             int* __restrict__ oslot_tok, float* __restrict__ oslot_gate,
                             float* __restrict__ loss_acc) {
  int b = blockIdx.x;
  int lane = threadIdx.x;             // 64 threads
  unsigned long long lmask = (1ULL << lane) - 1ULL;
  int cnt1[4] = {0, 0, 0, 0};
  float accProxy[4] = {0.f, 0.f, 0.f, 0.f};

  // ---- pass A: softmax, top2, mask_1 cumsum ----
  for (int ch = 0; ch < N_ / 64; ++ch) {
    int t = b * N_ + ch * 64 + lane;
    float4 l4 = ((const float4*)logits)[t];
    float p[4];
    {
      float m = fmaxf(fmaxf(l4.x, l4.y), fmaxf(l4.z, l4.w));
      p[0] = expf(l4.x - m); p[1] = expf(l4.y - m); p[2] = expf(l4.z - m); p[3] = expf(l4.w - m);
      float inv = 1.f / (p[0] + p[1] + p[2] + p[3]);
      p[0] *= inv; p[1] *= inv; p[2] *= inv; p[3] *= inv;
    }
    int i1 = 0; float g1 = p[0];
#pragma unroll
    for (int g = 1; g < 4; ++g) if (p[g] > g1) { g1 = p[g]; i1 = g; }
    int i2 = 0; float g2 = -1.f;
#pragma unroll
    for (int g = 0; g < 4; ++g) if (g != i1 && p[g] > g2) { g2 = p[g]; i2 = g; }
    float denom = g1 + g2 + EPS_;
    float g1n = g1 / denom, g2n = g2 / denom;
    accProxy[0] += p[0]; accProxy[1] += p[1]; accProxy[2] += p[2]; accProxy[3] += p[3];

    int pos1 = 0;
#pragma unroll
    for (int e = 0; e < 4; ++e) {
      unsigned long long mb = __ballot(i1 == e);
      if (i1 == e) pos1 = cnt1[e] + (int)__popcll(mb & lmask);
      cnt1[e] += (int)__popcll(mb);
    }
    bool kept1 = pos1 < CO_;
    t_idx1[t] = i1; t_idx2[t] = i2; t_pos1[t] = pos1;
    t_g1[t] = kept1 ? g1n : 0.f;
    t_g2[t] = g2n;  // provisional; finalized in pass B
    if (kept1) {
      int s = (i1 * B_ + b) * CO_ + pos1;
      oslot_tok[s] = t; oslot_gate[s] = g1n;
    }
  }

  // ---- loss_o contribution (pre-truncation density) ----
#pragma unroll
  for (int e = 0; e < 4; ++e) {
    float v = accProxy[e];
#pragma unroll
    for (int o = 32; o > 0; o >>= 1) v += __shfl_xor(v, o, 64);
    accProxy[e] = v;
  }
  if (lane == 0) {
    float part = 0.f;
#pragma unroll
    for (int e = 0; e < 4; ++e)
      part += (accProxy[e] / (float)N_) * ((float)cnt1[e] / (float)N_);
    atomicAdd(loss_acc, part * 16.f / (float)(B_ * EO_));
  }

  // ---- pass B: mask_2 cumsum offset by truncated mask_1 count ----
  int cnt2[4];
#pragma unroll
  for (int e = 0; e < 4; ++e) cnt2[e] = cnt1[e] < CO_ ? cnt1[e] : CO_;
  for (int ch = 0; ch < N_ / 64; ++ch) {
    int t = b * N_ + ch * 64 + lane;
    int i2 = t_idx2[t];
    int pos2 = 0;
#pragma unroll
    for (int e = 0; e < 4; ++e) {
      unsigned long long mb = __ballot(i2 == e);
      if (i2 == e) pos2 = cnt2[e] + (int)__popcll(mb & lmask);
      cnt2[e] += (int)__popcll(mb);
    }
    bool kept2 = pos2 < CO_;
    float g2n = t_g2[t];
    t_pos2[t] = pos2;
    t_g2[t] = kept2 ? g2n : 0.f;
    if (kept2) {
      int s = (i2 * B_ + b) * CO_ + pos2;
      oslot_tok[s] = t; oslot_gate[s] = g2n;
    }
  }
}

// ---------------- K3: inner gate logits per outer slot ----------------
__global__ void k_inner_logits(const float* __restrict__ x, const float* __restrict__ wgi,
                               const int* __restrict__ oslot_tok, float* __restrict__ ilogits) {
  int wave = (blockIdx.x * blockDim.x + threadIdx.x) >> 6;  // slot id [0,20480)
  int lane = threadIdx.x & 63;
  int e = wave / (B_ * CO_);
  int tok = oslot_tok[wave];
  float a0 = 0.f, a1 = 0.f, a2 = 0.f, a3 = 0.f;
  if (tok >= 0) {
    const float*  xr = x + (size_t)tok * D_;
    const float4* w4 = (const float4*)wgi + (size_t)e * D_;
#pragma unroll
    for (int i = 0; i < 16; ++i) {
      int d = i * 64 + lane;
      float xv = xr[d];
      float4 wv = w4[d];
      a0 += xv * wv.x; a1 += xv * wv.y; a2 += xv * wv.z; a3 += xv * wv.w;
    }
  }
#pragma unroll
  for (int o = 32; o > 0; o >>= 1) {
    a0 += __shfl_xor(a0, o, 64); a1 += __shfl_xor(a1, o, 64);
    a2 += __shfl_xor(a2, o, 64); a3 += __shfl_xor(a3, o, 64);
  }
  if (lane == 0) ((float4*)ilogits)[wave] = make_float4(a0, a1, a2, a3);
}

// ---------------- K4: inner top-2 gating with importance (one wave per (e,b)) ----------------
__global__ void k_inner_gate(const float* __restrict__ ilogits,
                             const int* __restrict__ oslot_tok, const float* __restrict__ oslot_gate,
                             int* __restrict__ os_f1, int* __restrict__ os_p1, float* __restrict__ os_g1,
                             int* __restrict__ os_f2, int* __restrict__ os_p2, float* __restrict__ os_g2,
                             int* __restrict__ islot_tok, float* __restrict__ loss_acc) {
  int eb = blockIdx.x;                  // 0..31
  int e = eb >> 3, b = eb & 7;
  int base = eb * CO_;
  int lane = threadIdx.x;
  unsigned long long lmask = (1ULL << lane) - 1ULL;
  int cnt1[4] = {0, 0, 0, 0};
  float accProxy[4] = {0.f, 0.f, 0.f, 0.f};

  // ---- pass A ----
  for (int ch = 0; ch < CO_ / 64; ++ch) {
    int s = base + ch * 64 + lane;
    float go = oslot_gate[s];
    bool eq1 = (go > 0.5f);            // importance == 1.0
    float4 l4 = ((const float4*)ilogits)[s];
    float p[4];
    {
      float m = fmaxf(fmaxf(l4.x, l4.y), fmaxf(l4.z, l4.w));
      p[0] = expf(l4.x - m); p[1] = expf(l4.y - m); p[2] = expf(l4.z - m); p[3] = expf(l4.w - m);
      float inv = 1.f / (p[0] + p[1] + p[2] + p[3]);
      p[0] *= inv; p[1] *= inv; p[2] *= inv; p[3] *= inv;
    }
    int i1 = 0; float g1raw = p[0];
#pragma unroll
    for (int g = 1; g < 4; ++g) if (p[g] > g1raw) { g1raw = p[g]; i1 = g; }
    int i2; float g2raw;
    if (eq1) {
      i2 = 0; g2raw = -1.f;
#pragma unroll
      for (int g = 0; g < 4; ++g) if (g != i1 && p[g] > g2raw) { g2raw = p[g]; i2 = g; }
    } else {            // importance 0.5 (or empty): mask_1 is zero -> argmax over full gates
      i2 = i1; g2raw = g1raw;
    }
    float gate1 = eq1 ? g1raw : 0.f;
    float gate2 = g2raw;
    float denom = gate1 + gate2 + EPS_;
    float g1n = gate1 / denom, g2n = gate2 / denom;
    if (eq1) { accProxy[0] += p[0]; accProxy[1] += p[1]; accProxy[2] += p[2]; accProxy[3] += p[3]; }

    int pos1 = 0;
#pragma unroll
    for (int g = 0; g < 4; ++g) {
      bool hit = eq1 && (i1 == g);
      unsigned long long mb = __ballot(hit);
      if (hit) pos1 = cnt1[g] + (int)__popcll(mb & lmask);
      cnt1[g] += (int)__popcll(mb);
    }
    bool kept1 = eq1 && (pos1 < CI_);
    os_f1[s] = i1; os_p1[s] = pos1; os_g1[s] = kept1 ? g1n : 0.f;
    os_f2[s] = i2; os_g2[s] = g2n;  // provisional
    if (kept1) islot_tok[((e * EI_ + i1) * B_ + b) * CI_ + pos1] = oslot_tok[s];
  }

  // ---- loss_i contribution ----
#pragma unroll
  for (int g = 0; g < 4; ++g) {
    float v = accProxy[g];
#pragma unroll
    for (int o = 32; o > 0; o >>= 1) v += __shfl_xor(v, o, 64);
    accProxy[g] = v;
  }
  if (lane == 0) {
    float part = 0.f;
#pragma unroll
    for (int g = 0; g < 4; ++g)
      part += (accProxy[g] / (float)CO_) * ((float)cnt1[g] / (float)CO_);
    atomicAdd(loss_acc, part * 16.f / (float)(EO_ * B_ * EI_));
  }

  // ---- pass B ----
  int cnt2[4];
#pragma unroll
  for (int g = 0; g < 4; ++g) cnt2[g] = cnt1[g] < CI_ ? cnt1[g] : CI_;
  for (int ch = 0; ch < CO_ / 64; ++ch) {
    int s = base + ch * 64 + lane;
    bool act2 = (oslot_gate[s] > 0.f);   // importance > 0
    int i2 = os_f2[s];
    int pos2 = 0;
#pragma unroll
    for (int g = 0; g < 4; ++g) {
      bool hit = act2 && (i2 == g);
      unsigned long long mb = __ballot(hit);
      if (hit) pos2 = cnt2[g] + (int)__popcll(mb & lmask);
      cnt2[g] += (int)__popcll(mb);
    }
    bool kept2 = act2 && (pos2 < CI_);
    float g2n = os_g2[s];
    os_p2[s] = pos2;
    os_g2[s] = kept2 ? g2n : 0.f;
    if (kept2) islot_tok[((e * EI_ + i2) * B_ + b) * CI_ + pos2] = oslot_tok[s];
  }
}

// ---------------- GEMM1: hidden = relu(X_gathered @ w1) , 64x64x16 fp32 tile ----------------
__global__ __launch_bounds__(256) void k_gemm_in(const float* __restrict__ x,
                                                 const float* __restrict__ w1,
                                                 const int* __restrict__ islot_tok,
                                                 float* __restrict__ hidden, int pair0) {
  __shared__ float As[16][64];
  __shared__ float Bs[16][64];
  int z = blockIdx.z;
  int pair = pair0 + z;
  int row0 = blockIdx.x * 64, col0 = blockIdx.y * 64;
  int tt = threadIdx.x;
  int a_row = tt >> 2, a_k = (tt & 3) << 2;
  int b_k = tt >> 4, b_n = (tt & 15) << 2;
  int tm = (tt >> 4) << 2, tn = (tt & 15) << 2;
  int tok = islot_tok[pair * 1600 + row0 + a_row];
  const float* arow = (tok >= 0) ? x + (size_t)tok * D_ : nullptr;
  const float* Bbase = w1 + (size_t)pair * D_ * H_;
  float acc[4][4] = {};
  for (int k0 = 0; k0 < D_; k0 += 16) {
    float4 av = arow ? *(const float4*)(arow + k0 + a_k) : make_float4(0.f, 0.f, 0.f, 0.f);
    As[a_k + 0][a_row] = av.x; As[a_k + 1][a_row] = av.y;
    As[a_k + 2][a_row] = av.z; As[a_k + 3][a_row] = av.w;
    *(float4*)&Bs[b_k][b_n] = *(const float4*)(Bbase + (size_t)(k0 + b_k) * H_ + col0 + b_n);
    __syncthreads();
#pragma unroll
    for (int k = 0; k < 16; ++k) {
      float a0 = As[k][tm], a1 = As[k][tm + 1], a2 = As[k][tm + 2], a3 = As[k][tm + 3];
      float b0 = Bs[k][tn], b1 = Bs[k][tn + 1], b2 = Bs[k][tn + 2], b3 = Bs[k][tn + 3];
      acc[0][0] += a0 * b0; acc[0][1] += a0 * b1; acc[0][2] += a0 * b2; acc[0][3] += a0 * b3;
      acc[1][0] += a1 * b0; acc[1][1] += a1 * b1; acc[1][2] += a1 * b2; acc[1][3] += a1 * b3;
      acc[2][0] += a2 * b0; acc[2][1] += a2 * b1; acc[2][2] += a2 * b2; acc[2][3] += a2 * b3;
      acc[3][0] += a3 * b0; acc[3][1] += a3 * b1; acc[3][2] += a3 * b2; acc[3][3] += a3 * b3;
    }
    __syncthreads();
  }
#pragma unroll
  for (int i = 0; i < 4; ++i) {
    float4 v = make_float4(fmaxf(acc[i][0], 0.f), fmaxf(acc[i][1], 0.f),
                           fmaxf(acc[i][2], 0.f), fmaxf(acc[i][3], 0.f));
    *(float4*)(hidden + (size_t)(z * 1600 + row0 + tm + i) * H_ + col0 + tn) = v;
  }
}

// ---------------- GEMM2: exp_out = hidden @ w2 ----------------
__global__ __launch_bounds__(256) void k_gemm_out(const float* __restrict__ hidden,
                                                  const float* __restrict__ w2,
                                                  float* __restrict__ exp_out, int pair0) {
  __shared__ float As[16][64];
  __shared__ float Bs[16][64];
  int z = blockIdx.z;
  int pair = pair0 + z;
  int row0 = blockIdx.x * 64, col0 = blockIdx.y * 64;
  int tt = threadIdx.x;
  int a_row = tt >> 2, a_k = (tt & 3) << 2;
  int b_k = tt >> 4, b_n = (tt & 15) << 2;
  int tm = (tt >> 4) << 2, tn = (tt & 15) << 2;
  const float* arow = hidden + (size_t)(z * 1600 + row0 + a_row) * H_;
  const float* Bbase = w2 + (size_t)pair * H_ * D_;
  float acc[4][4] = {};
  for (int k0 = 0; k0 < H_; k0 += 16) {
    float4 av = *(const float4*)(arow + k0 + a_k);
    As[a_k + 0][a_row] = av.x; As[a_k + 1][a_row] = av.y;
    As[a_k + 2][a_row] = av.z; As[a_k + 3][a_row] = av.w;
    *(float4*)&Bs[b_k][b_n] = *(const float4*)(Bbase + (size_t)(k0 + b_k) * D_ + col0 + b_n);
    __syncthreads();
#pragma unroll
    for (int k = 0; k < 16; ++k) {
      float a0 = As[k][tm], a1 = As[k][tm + 1], a2 = As[k][tm + 2], a3 = As[k][tm + 3];
      float b0 = Bs[k][tn], b1 = Bs[k][tn + 1], b2 = Bs[k][tn + 2], b3 = Bs[k][tn + 3];
      acc[0][0] += a0 * b0; acc[0][1] += a0 * b1; acc[0][2] += a0 * b2; acc[0][3] += a0 * b3;
      acc[1][0] += a1 * b0; acc[1][1] += a1 * b1; acc[1][2] += a1 * b2; acc[1][3] += a1 * b3;
      acc[2][0] += a2 * b0; acc[2][1] += a2 * b1; acc[2][2] += a2 * b2; acc[2][3] += a2 * b3;
      acc[3][0] += a3 * b0; acc[3][1] += a3 * b1; acc[3][2] += a3 * b2; acc[3][3] += a3 * b3;
    }
    __syncthreads();
  }
#pragma unroll
  for (int i = 0; i < 4; ++i) {
    float4 v = make_float4(acc[i][0], acc[i][1], acc[i][2], acc[i][3]);
    *(float4*)(exp_out + (size_t)(pair * 1600 + row0 + tm + i) * D_ + col0 + tn) = v;
  }
}

// ---------------- K6: fused inner+outer combine (per-token <=4 row gather) ----------------
__global__ void k_combine(const float* __restrict__ exp_out,
                          const int* __restrict__ t_idx1, const int* __restrict__ t_idx2,
                          const int* __restrict__ t_pos1, const int* __restrict__ t_pos2,
                          const float* __restrict__ t_g1, const float* __restrict__ t_g2,
                          const int* __restrict__ os_f1, const int* __restrict__ os_p1,
                          const float* __restrict__ os_g1,
                          const int* __restrict__ os_f2, const int* __restrict__ os_p2,
                          const float* __restrict__ os_g2,
                          float* __restrict__ out) {
  int t = blockIdx.x;
  int b = t >> 11;
  float coef[4]; int rows[4]; int nr = 0;
  float gv[2] = { t_g1[t], t_g2[t] };
  int   eo[2] = { t_idx1[t], t_idx2[t] };
  int   cp[2] = { t_pos1[t], t_pos2[t] };
#pragma unroll
  for (int q = 0; q < 2; ++q) {
    if (gv[q] == 0.f) continue;
    int e = eo[q];
    int s = (e * B_ + b) * CO_ + cp[q];
    float gi1 = os_g1[s], gi2 = os_g2[s];
    if (gi1 != 0.f) { coef[nr] = gv[q] * gi1; rows[nr] = (e * EI_ + os_f1[s]) * 1600 + b * CI_ + os_p1[s]; ++nr; }
    if (gi2 != 0.f) { coef[nr] = gv[q] * gi2; rows[nr] = (e * EI_ + os_f2[s]) * 1600 + b * CI_ + os_p2[s]; ++nr; }
  }
  int d0 = threadIdx.x * 4;
  float4 acc = make_float4(0.f, 0.f, 0.f, 0.f);
  for (int r = 0; r < nr; ++r) {
    float4 v = *(const float4*)(exp_out + (size_t)rows[r] * D_ + d0);
    acc.x += coef[r] * v.x; acc.y += coef[r] * v.y;
    acc.z += coef[r] * v.z; acc.w += coef[r] * v.w;
  }
  *(float4*)(out + (size_t)t * D_ + d0) = acc;
}

__global__ void k_loss(const float* __restrict__ loss_acc, float* __restrict__ out_loss) {
  if (threadIdx.x == 0 && blockIdx.x == 0) out_loss[0] = loss_acc[0] * 0.01f;
}

// ---------------- host ----------------
extern "C" void kernel_launch(void* const* d_in, const int* in_sizes, int n_in,
                              void* d_out, int out_size, void* d_ws, size_t ws_size,
                              hipStream_t stream) {
  const float* x   = (const float*)d_in[0];
  const float* wgo = (const float*)d_in[1];
  const float* wgi = (const float*)d_in[2];
  const float* w1  = (const float*)d_in[3];
  const float* w2  = (const float*)d_in[4];
  float* out = (float*)d_out;

  char* ws = (char*)d_ws;
  size_t off = 0;
  auto alloc = [&](size_t bytes) -> void* {
    void* p = ws + off;
    off = (off + bytes + 255) & ~(size_t)255;
    return p;
  };
  float* logits_o   = (float*)alloc((size_t)NTOK * 4 * sizeof(float));
  float* ilogits    = (float*)alloc((size_t)NSLOT * 4 * sizeof(float));
  int*   t_idx1     = (int*)alloc((size_t)NTOK * sizeof(int));
  int*   t_idx2     = (int*)alloc((size_t)NTOK * sizeof(int));
  int*   t_pos1     = (int*)alloc((size_t)NTOK * sizeof(int));
  int*   t_pos2     = (int*)alloc((size_t)NTOK * sizeof(int));
  float* t_g1       = (float*)alloc((size_t)NTOK * sizeof(float));
  float* t_g2       = (float*)alloc((size_t)NTOK * sizeof(float));
  int*   oslot_tok  = (int*)alloc((size_t)NSLOT * sizeof(int));
  float* oslot_gate = (float*)alloc((size_t)NSLOT * sizeof(float));
  int*   os_f1      = (int*)alloc((size_t)NSLOT * sizeof(int));
  int*   os_p1      = (int*)alloc((size_t)NSLOT * sizeof(int));
  float* os_g1      = (float*)alloc((size_t)NSLOT * sizeof(float));
  int*   os_f2      = (int*)alloc((size_t)NSLOT * sizeof(int));
  int*   os_p2      = (int*)alloc((size_t)NSLOT * sizeof(int));
  float* os_g2      = (float*)alloc((size_t)NSLOT * sizeof(float));
  int*   islot_tok  = (int*)alloc((size_t)NISL * sizeof(int));
  float* loss_acc   = (float*)alloc(256);
  float* hidden     = (float*)alloc((size_t)4 * 1600 * H_ * sizeof(float));   // 4 pairs at a time
  float* exp_out    = (float*)alloc((size_t)16 * 1600 * D_ * sizeof(float));  // all pairs

  hipMemsetAsync(oslot_tok, 0xFF, (size_t)NSLOT * sizeof(int), stream);
  hipMemsetAsync(oslot_gate, 0, (size_t)NSLOT * sizeof(float), stream);
  hipMemsetAsync(islot_tok, 0xFF, (size_t)NISL * sizeof(int), stream);
  hipMemsetAsync(loss_acc, 0, sizeof(float), stream);

  k_outer_logits<<<NTOK / 4, 256, 0, stream>>>(x, wgo, logits_o);
  k_outer_gate<<<B_, 64, 0, stream>>>(logits_o, t_idx1, t_idx2, t_pos1, t_pos2,
                                      t_g1, t_g2, oslot_tok, oslot_gate, loss_acc);
  k_inner_logits<<<NSLOT / 4, 256, 0, stream>>>(x, wgi, oslot_tok, ilogits);
  k_inner_gate<<<EO_ * B_, 64, 0, stream>>>(ilogits, oslot_tok, oslot_gate,
                                            os_f1, os_p1, os_g1, os_f2, os_p2, os_g2,
                                            islot_tok, loss_acc);
  for (int g = 0; g < 16; g += 4) {
    k_gemm_in<<<dim3(25, H_ / 64, 4), 256, 0, stream>>>(x, w1, islot_tok, hidden, g);
    k_gemm_out<<<dim3(25, D_ / 64, 4), 256, 0, stream>>>(hidden, w2, exp_out, g);
  }
  k_combine<<<NTOK, 256, 0, stream>>>(exp_out, t_idx1, t_idx2, t_pos1, t_pos2, t_g1, t_g2,
                                      os_f1, os_p1, os_g1, os_f2, os_p2, os_g2, out);
  k_loss<<<1, 64, 0, stream>>>(loss_acc, out + (size_t)NTOK * D_);
}